// Round 1
// baseline (1397.941 us; speedup 1.0000x reference)
//
#include <hip/hip_runtime.h>
#include <stdint.h>

#define NN 51200
#define NE 409600
#define NG 256
#define DD 128

typedef __attribute__((ext_vector_type(4))) float f32x4;
typedef __attribute__((ext_vector_type(8))) __bf16 bf16x8;
typedef __attribute__((ext_vector_type(4))) unsigned short u16x4;

static __device__ __forceinline__ unsigned short f2bf(float f) {
    unsigned u = __float_as_uint(f);
    return (unsigned short)((u + 0x7FFFu + ((u >> 16) & 1u)) >> 16);
}
static __device__ __forceinline__ float lrelu(float x) {
    return x > 0.f ? x : 0.01f * x;
}

// ---------------------------------------------------------------------------
// K0: transpose + cast the 4 big weight matrices to bf16 [N=128][K] layout.
// wt0: [2][128][384]  (mlp 0 = node/msg MLP, 1 = edge MLP), wt1: [2][128][128]
// ---------------------------------------------------------------------------
__global__ void k_weights(const float* __restrict__ nW0, const float* __restrict__ nW1,
                          const float* __restrict__ eW0, const float* __restrict__ eW1,
                          unsigned short* __restrict__ wt0, unsigned short* __restrict__ wt1)
{
    int i = blockIdx.x * 256 + threadIdx.x;           // 512 blocks * 256 = 131072
    if (i < 98304) {
        int m = i / 49152;
        int j = i - m * 49152;
        int k = j >> 7, n = j & 127;
        const float* W = m ? eW0 : nW0;
        wt0[m * 49152 + n * 384 + k] = f2bf(W[j]);
    } else {
        int j = i - 98304;
        int m = j >> 14;
        int jj = j & 16383;
        int k = jj >> 7, n = jj & 127;
        const float* W = m ? eW1 : nW1;
        wt1[m * 16384 + n * 128 + k] = f2bf(W[jj]);
    }
}

// ---------------------------------------------------------------------------
// Per-graph segment sums (f32). grid (G, splits), block 128 (one col/thread).
// ---------------------------------------------------------------------------
__global__ void k_segsum(const float* __restrict__ x, const int* __restrict__ counts,
                         float* __restrict__ out)
{
    int g = blockIdx.x;
    int start = 0;
    for (int i = 0; i < g; i++) start += counts[i];
    int cnt = counts[g];
    int splits = gridDim.y;
    int per = (cnt + splits - 1) / splits;
    int r0 = blockIdx.y * per;
    int r1 = r0 + per; if (r1 > cnt) r1 = cnt;
    if (r0 >= r1) return;
    int c = threadIdx.x;
    float acc = 0.f;
    for (int r = r0; r < r1; r++) acc += x[(size_t)(start + r) * DD + c];
    atomicAdd(out + g * DD + c, acc);
}

// ---------------------------------------------------------------------------
// Main fused edge kernel: per 128-edge tile, one of the two edge-level MLPs.
//   layer1: D1[n][m] = sum_k W0t[n][k] * concat[m][k]   (MFMA, bf16)
//   layer2: D2[n2][m] = sum_k W1t[n2][k] * H[m][k]
// mlp==0: scatter-add result into out_nodes[receivers]; mlp==1: store new_edges.
// LDS 52224 B -> 3 blocks/CU.
// ---------------------------------------------------------------------------
__global__ __launch_bounds__(256, 3) void k_edge(
    const float* __restrict__ nodes, const float* __restrict__ edges,
    const int* __restrict__ senders, const int* __restrict__ receivers,
    const unsigned short* __restrict__ wt0, const unsigned short* __restrict__ wt1,
    const float* __restrict__ nb0, const float* __restrict__ nb1,
    const float* __restrict__ eb0, const float* __restrict__ eb1,
    float* __restrict__ out_nodes, float* __restrict__ out_edges)
{
    __shared__ char lds[52224];
    unsigned short* A1 = (unsigned short*)lds;                 // [128][72] bf16 (pad 8 -> 4-bank row rotation)
    unsigned short* B1 = (unsigned short*)(lds + 18432);       // [128][64] bf16 (DMA, unpadded)
    unsigned short* A2 = (unsigned short*)lds;                 // [128][136] bf16 (aliases A1+B1, pad 8)
    unsigned short* B2 = (unsigned short*)(lds + 34816);       // [128][64] bf16 (DMA)
    int* ldsSend = (int*)(lds + 51200);
    int* ldsRecv = (int*)(lds + 51712);

    const int t = threadIdx.x;
    const int mlp = blockIdx.y;
    const size_t e0 = (size_t)blockIdx.x * 128;

    if (t < 128) ldsSend[t] = senders[e0 + t];
    else         ldsRecv[t - 128] = receivers[e0 + t - 128];
    __syncthreads();

    const int rowIdx = t >> 4;     // staging: 16 threads per row
    const int c4 = t & 15;
    int snd[8], rcv[8];
    #pragma unroll
    for (int i = 0; i < 8; i++) {
        snd[i] = ldsSend[i * 16 + rowIdx];
        rcv[i] = ldsRecv[i * 16 + rowIdx];
    }

    const int w = t >> 6, l = t & 63;
    const int l15 = l & 15, q = l >> 4;
    const int wn = (w >> 1) * 64;   // feature-dim half owned by this wave
    const int wm = (w & 1) * 64;    // edge-dim half

    const unsigned short* wt0m = wt0 + (size_t)mlp * 49152;
    const unsigned short* wt1m = wt1 + (size_t)mlp * 16384;
    const float* b0 = mlp ? eb0 : nb0;
    const float* b1 = mlp ? eb1 : nb1;

    const f32x4 vzero = {0.f, 0.f, 0.f, 0.f};
    f32x4 acc[4][4];
    #pragma unroll
    for (int i1 = 0; i1 < 4; i1++)
        #pragma unroll
        for (int i2 = 0; i2 < 4; i2++) acc[i1][i2] = vzero;

    // ---------------- layer 1: K = 384, 6 chunks of 64 ----------------
    #pragma unroll
    for (int c = 0; c < 6; c++) {
        // stage A (gather + f32->bf16)
        #pragma unroll
        for (int i = 0; i < 8; i++) {
            int m = i * 16 + rowIdx;
            const float* p;
            if (c < 2)      p = nodes + (size_t)snd[i] * DD + c * 64 + c4 * 4;
            else if (c < 4) p = nodes + (size_t)rcv[i] * DD + (c - 2) * 64 + c4 * 4;
            else            p = edges + (e0 + m) * DD + (c - 4) * 64 + c4 * 4;
            f32x4 v = *(const f32x4*)p;
            u16x4 h;
            h[0] = f2bf(v[0]); h[1] = f2bf(v[1]); h[2] = f2bf(v[2]); h[3] = f2bf(v[3]);
            *(u16x4*)(A1 + m * 72 + c4 * 4) = h;
        }
        // stage B (async DMA, 16B/lane)
        #pragma unroll
        for (int i = 0; i < 4; i++) {
            int idx = i * 256 + w * 64 + l;
            const unsigned short* g = wt0m + (idx >> 3) * 384 + c * 64 + (idx & 7) * 8;
            void* lb = (void*)(lds + 18432 + (i * 256 + w * 64) * 16);
            __builtin_amdgcn_global_load_lds(
                (const __attribute__((address_space(1))) void*)g,
                (__attribute__((address_space(3))) void*)lb, 16, 0, 0);
        }
        __syncthreads();
        #pragma unroll
        for (int kk = 0; kk < 2; kk++) {
            bf16x8 af[4], bfr[4];
            #pragma unroll
            for (int tn = 0; tn < 4; tn++)
                af[tn] = *(const bf16x8*)(B1 + (wn + tn * 16 + l15) * 64 + kk * 32 + q * 8);
            #pragma unroll
            for (int tm = 0; tm < 4; tm++)
                bfr[tm] = *(const bf16x8*)(A1 + (wm + tm * 16 + l15) * 72 + kk * 32 + q * 8);
            #pragma unroll
            for (int tn = 0; tn < 4; tn++)
                #pragma unroll
                for (int tm = 0; tm < 4; tm++)
                    acc[tn][tm] = __builtin_amdgcn_mfma_f32_16x16x32_bf16(
                        af[tn], bfr[tm], acc[tn][tm], 0, 0, 0);
        }
        __syncthreads();
    }

    // ---------------- layer-1 epilogue -> A2[m][n] (bf16) ----------------
    #pragma unroll
    for (int tn = 0; tn < 4; tn++) {
        float bb[4];
        #pragma unroll
        for (int r = 0; r < 4; r++) bb[r] = b0[wn + tn * 16 + q * 4 + r];
        #pragma unroll
        for (int tm = 0; tm < 4; tm++) {
            u16x4 h;
            #pragma unroll
            for (int r = 0; r < 4; r++) {
                float v = lrelu(acc[tn][tm][r] + bb[r]);
                h[r] = f2bf(v);
            }
            int m = wm + tm * 16 + l15;
            *(u16x4*)(A2 + m * 136 + wn + tn * 16 + q * 4) = h;
        }
    }
    // stage B2 chunk 0 (disjoint LDS region; drains at the barrier)
    #pragma unroll
    for (int i = 0; i < 4; i++) {
        int idx = i * 256 + w * 64 + l;
        const unsigned short* g = wt1m + (idx >> 3) * 128 + (idx & 7) * 8;
        void* lb = (void*)(lds + 34816 + (i * 256 + w * 64) * 16);
        __builtin_amdgcn_global_load_lds(
            (const __attribute__((address_space(1))) void*)g,
            (__attribute__((address_space(3))) void*)lb, 16, 0, 0);
    }
    __syncthreads();

    #pragma unroll
    for (int i1 = 0; i1 < 4; i1++)
        #pragma unroll
        for (int i2 = 0; i2 < 4; i2++) acc[i1][i2] = vzero;

    // ---------------- layer 2: K = 128, 2 chunks of 64 ----------------
    #pragma unroll
    for (int c2 = 0; c2 < 2; c2++) {
        if (c2 == 1) {
            __syncthreads();
            #pragma unroll
            for (int i = 0; i < 4; i++) {
                int idx = i * 256 + w * 64 + l;
                const unsigned short* g = wt1m + (idx >> 3) * 128 + 64 + (idx & 7) * 8;
                void* lb = (void*)(lds + 34816 + (i * 256 + w * 64) * 16);
                __builtin_amdgcn_global_load_lds(
                    (const __attribute__((address_space(1))) void*)g,
                    (__attribute__((address_space(3))) void*)lb, 16, 0, 0);
            }
            __syncthreads();
        }
        #pragma unroll
        for (int kk = 0; kk < 2; kk++) {
            bf16x8 af[4], bfr[4];
            #pragma unroll
            for (int tn = 0; tn < 4; tn++)
                af[tn] = *(const bf16x8*)(B2 + (wn + tn * 16 + l15) * 64 + kk * 32 + q * 8);
            #pragma unroll
            for (int tm = 0; tm < 4; tm++)
                bfr[tm] = *(const bf16x8*)(A2 + (wm + tm * 16 + l15) * 136 + c2 * 64 + kk * 32 + q * 8);
            #pragma unroll
            for (int tn = 0; tn < 4; tn++)
                #pragma unroll
                for (int tm = 0; tm < 4; tm++)
                    acc[tn][tm] = __builtin_amdgcn_mfma_f32_16x16x32_bf16(
                        af[tn], bfr[tm], acc[tn][tm], 0, 0, 0);
        }
    }

    // ---------------- layer-2 epilogue ----------------
    #pragma unroll
    for (int tn = 0; tn < 4; tn++) {
        float bb[4];
        #pragma unroll
        for (int r = 0; r < 4; r++) bb[r] = b1[wn + tn * 16 + q * 4 + r];
        #pragma unroll
        for (int tm = 0; tm < 4; tm++) {
            int m = wm + tm * 16 + l15;
            int n0 = wn + tn * 16 + q * 4;
            f32x4 v;
            #pragma unroll
            for (int r = 0; r < 4; r++) v[r] = lrelu(acc[tn][tm][r] + bb[r]);
            if (mlp) {
                *(f32x4*)(out_edges + (e0 + m) * DD + n0) = v;
            } else {
                float* p = out_nodes + (size_t)ldsRecv[m] * DD + n0;
                #pragma unroll
                for (int r = 0; r < 4; r++) atomicAdd(p + r, v[r]);
            }
        }
    }
}

// ---------------------------------------------------------------------------
// Global-path MLPs in f32 (tiny). grid (16, 3): 16 row-blocks x 3 MLPs.
// Writes into fargs[256][384] concat layout.
// ---------------------------------------------------------------------------
__global__ void k_globalA(const float* __restrict__ gin, const float* __restrict__ sn,
                          const float* __restrict__ se,
                          const float* __restrict__ W0a, const float* __restrict__ b0a,
                          const float* __restrict__ W1a, const float* __restrict__ b1a,
                          const float* __restrict__ W0b, const float* __restrict__ b0b,
                          const float* __restrict__ W1b, const float* __restrict__ b1b,
                          const float* __restrict__ W0c, const float* __restrict__ b0c,
                          const float* __restrict__ W1c, const float* __restrict__ b1c,
                          float* __restrict__ fargs)
{
    __shared__ float xT[128 * 16];
    __shared__ float hT[128 * 16];
    const int m = blockIdx.y;
    const float* X   = m == 0 ? gin : (m == 1 ? sn : se);
    const float* W0  = m == 0 ? W0a : (m == 1 ? W0b : W0c);
    const float* B0  = m == 0 ? b0a : (m == 1 ? b0b : b0c);
    const float* W1  = m == 0 ? W1a : (m == 1 ? W1b : W1c);
    const float* B1v = m == 0 ? b1a : (m == 1 ? b1b : b1c);
    const int g0 = blockIdx.x * 16, t = threadIdx.x;
    #pragma unroll
    for (int i = 0; i < 8; i++) {
        int idx = i * 256 + t, r = idx >> 7, k = idx & 127;
        xT[k * 16 + r] = X[(size_t)(g0 + r) * DD + k];
    }
    __syncthreads();
    const int n = t & 127, rb = (t >> 7) * 8;
    float a[8] = {};
    for (int k = 0; k < 128; k++) {
        float wv = W0[k * 128 + n];
        #pragma unroll
        for (int j = 0; j < 8; j++) a[j] += xT[k * 16 + rb + j] * wv;
    }
    float bv = B0[n];
    #pragma unroll
    for (int j = 0; j < 8; j++) hT[n * 16 + rb + j] = lrelu(a[j] + bv);
    __syncthreads();
    float a2[8] = {};
    for (int k = 0; k < 128; k++) {
        float wv = W1[k * 128 + n];
        #pragma unroll
        for (int j = 0; j < 8; j++) a2[j] += hT[k * 16 + rb + j] * wv;
    }
    bv = B1v[n];
    #pragma unroll
    for (int j = 0; j < 8; j++)
        fargs[(size_t)(g0 + rb + j) * 384 + m * 128 + n] = lrelu(a2[j] + bv);
}

__global__ void k_globalB(const float* __restrict__ fargs,
                          const float* __restrict__ W0, const float* __restrict__ B0,
                          const float* __restrict__ W1, const float* __restrict__ B1v,
                          float* __restrict__ outg)
{
    __shared__ float xT[384 * 16];
    __shared__ float hT[128 * 16];
    const int g0 = blockIdx.x * 16, t = threadIdx.x;
    for (int r = 0; r < 16; r++)
        for (int k = t; k < 384; k += 256)
            xT[k * 16 + r] = fargs[(size_t)(g0 + r) * 384 + k];
    __syncthreads();
    const int n = t & 127, rb = (t >> 7) * 8;
    float a[8] = {};
    for (int k = 0; k < 384; k++) {
        float wv = W0[k * 128 + n];
        #pragma unroll
        for (int j = 0; j < 8; j++) a[j] += xT[k * 16 + rb + j] * wv;
    }
    float bv = B0[n];
    #pragma unroll
    for (int j = 0; j < 8; j++) hT[n * 16 + rb + j] = lrelu(a[j] + bv);
    __syncthreads();
    float a2[8] = {};
    for (int k = 0; k < 128; k++) {
        float wv = W1[k * 128 + n];
        #pragma unroll
        for (int j = 0; j < 8; j++) a2[j] += hT[k * 16 + rb + j] * wv;
    }
    bv = B1v[n];
    #pragma unroll
    for (int j = 0; j < 8; j++)
        outg[(size_t)(g0 + rb + j) * DD + n] = lrelu(a2[j] + bv);
}

extern "C" void kernel_launch(void* const* d_in, const int* in_sizes, int n_in,
                              void* d_out, int out_size, void* d_ws, size_t ws_size,
                              hipStream_t stream)
{
    const float* nodes     = (const float*)d_in[0];
    const float* edges     = (const float*)d_in[1];
    const float* globals_  = (const float*)d_in[2];
    const int*   senders   = (const int*)d_in[3];
    const int*   receivers = (const int*)d_in[4];
    const int*   n_node    = (const int*)d_in[5];
    const int*   n_edge    = (const int*)d_in[6];
    const float* node_W0 = (const float*)d_in[7];
    const float* node_b0 = (const float*)d_in[8];
    const float* node_W1 = (const float*)d_in[9];
    const float* node_b1 = (const float*)d_in[10];
    const float* edge_W0 = (const float*)d_in[11];
    const float* edge_b0 = (const float*)d_in[12];
    const float* edge_W1 = (const float*)d_in[13];
    const float* edge_b1 = (const float*)d_in[14];
    const float* glob_W0 = (const float*)d_in[15];
    const float* glob_b0 = (const float*)d_in[16];
    const float* glob_W1 = (const float*)d_in[17];
    const float* glob_b1 = (const float*)d_in[18];
    const float* gnode_W0 = (const float*)d_in[19];
    const float* gnode_b0 = (const float*)d_in[20];
    const float* gnode_W1 = (const float*)d_in[21];
    const float* gnode_b1 = (const float*)d_in[22];
    const float* gedge_W0 = (const float*)d_in[23];
    const float* gedge_b0 = (const float*)d_in[24];
    const float* gedge_W1 = (const float*)d_in[25];
    const float* gedge_b1 = (const float*)d_in[26];
    const float* fin_W0 = (const float*)d_in[27];
    const float* fin_b0 = (const float*)d_in[28];
    const float* fin_W1 = (const float*)d_in[29];
    const float* fin_b1 = (const float*)d_in[30];

    float* out_nodes = (float*)d_out;
    float* out_edges = out_nodes + (size_t)NN * DD;
    float* out_glob  = out_edges + (size_t)NE * DD;

    char* ws = (char*)d_ws;
    unsigned short* wt0 = (unsigned short*)ws;             // 196608 B
    unsigned short* wt1 = (unsigned short*)(ws + 196608);  // 65536 B
    float* sn    = (float*)(ws + 262144);                  // 131072 B
    float* se    = (float*)(ws + 393216);                  // 131072 B
    float* fargs = (float*)(ws + 524288);                  // 393216 B

    // zero the atomic-accumulated regions
    hipMemsetAsync(out_nodes, 0, (size_t)NN * DD * sizeof(float), stream);
    hipMemsetAsync(sn, 0, 262144, stream);

    k_weights<<<512, 256, 0, stream>>>(node_W0, node_W1, edge_W0, edge_W1, wt0, wt1);
    k_segsum<<<dim3(NG, 2), 128, 0, stream>>>(nodes, n_node, sn);
    k_segsum<<<dim3(NG, 8), 128, 0, stream>>>(edges, n_edge, se);
    k_edge<<<dim3(NE / 128, 2), 256, 0, stream>>>(nodes, edges, senders, receivers,
        wt0, wt1, node_b0, node_b1, edge_b0, edge_b1, out_nodes, out_edges);
    k_globalA<<<dim3(16, 3), 256, 0, stream>>>(globals_, sn, se,
        glob_W0, glob_b0, glob_W1, glob_b1,
        gnode_W0, gnode_b0, gnode_W1, gnode_b1,
        gedge_W0, gedge_b0, gedge_W1, gedge_b1, fargs);
    k_globalB<<<16, 256, 0, stream>>>(fargs, fin_W0, fin_b0, fin_W1, fin_b1, out_glob);
}

// Round 2
// 929.887 us; speedup vs baseline: 1.5033x; 1.5033x over previous
//
#include <hip/hip_runtime.h>
#include <stdint.h>

#define NN 51200
#define NE 409600
#define NG 256
#define DD 128

typedef __attribute__((ext_vector_type(4))) float f32x4;
typedef __attribute__((ext_vector_type(2))) float f32x2;
typedef __attribute__((ext_vector_type(8))) __bf16 bf16x8;
typedef __attribute__((ext_vector_type(4))) unsigned short u16x4;

static __device__ __forceinline__ unsigned short f2bf(float f) {
    unsigned u = __float_as_uint(f);
    return (unsigned short)((u + 0x7FFFu + ((u >> 16) & 1u)) >> 16);
}
static __device__ __forceinline__ float lrelu(float x) {
    return x > 0.f ? x : 0.01f * x;
}

// ---------------------------------------------------------------------------
// K0: transpose + cast the 4 big weight matrices to bf16 [N=128][K] layout.
// ---------------------------------------------------------------------------
__global__ void k_weights(const float* __restrict__ nW0, const float* __restrict__ nW1,
                          const float* __restrict__ eW0, const float* __restrict__ eW1,
                          unsigned short* __restrict__ wt0, unsigned short* __restrict__ wt1)
{
    int i = blockIdx.x * 256 + threadIdx.x;
    if (i < 98304) {
        int m = i / 49152;
        int j = i - m * 49152;
        int k = j >> 7, n = j & 127;
        const float* W = m ? eW0 : nW0;
        wt0[m * 49152 + n * 384 + k] = f2bf(W[j]);
    } else {
        int j = i - 98304;
        int m = j >> 14;
        int jj = j & 16383;
        int k = jj >> 7, n = jj & 127;
        const float* W = m ? eW1 : nW1;
        wt1[m * 16384 + n * 128 + k] = f2bf(W[jj]);
    }
}

// ---------------------------------------------------------------------------
// Per-graph segment sums (f32).
// ---------------------------------------------------------------------------
__global__ void k_segsum(const float* __restrict__ x, const int* __restrict__ counts,
                         float* __restrict__ out)
{
    int g = blockIdx.x;
    int start = 0;
    for (int i = 0; i < g; i++) start += counts[i];
    int cnt = counts[g];
    int splits = gridDim.y;
    int per = (cnt + splits - 1) / splits;
    int r0 = blockIdx.y * per;
    int r1 = r0 + per; if (r1 > cnt) r1 = cnt;
    if (r0 >= r1) return;
    int c = threadIdx.x;
    float acc = 0.f;
    for (int r = r0; r < r1; r++) acc += x[(size_t)(start + r) * DD + c];
    atomicAdd(out + g * DD + c, acc);
}

// ---------------------------------------------------------------------------
// CSR build: histogram, single-block exclusive scan, scatter permutation.
// cursor is initialized by k_scan to the exclusive offsets and mutated by
// k_scatter into end-pointers (end = start + count).
// ---------------------------------------------------------------------------
__global__ void k_hist(const int* __restrict__ recv, int* __restrict__ counts)
{
    int e = blockIdx.x * 256 + threadIdx.x;
    if (e < NE) atomicAdd(&counts[recv[e]], 1);
}

__global__ void k_scan(const int* __restrict__ counts, int* __restrict__ cursor)
{
    __shared__ int s[1024];
    const int t = threadIdx.x;
    const int base = t * 50;   // 1024 * 50 = 51200 exact
    int sum = 0;
    for (int i = 0; i < 50; i++) sum += counts[base + i];
    s[t] = sum;
    __syncthreads();
    for (int off = 1; off < 1024; off <<= 1) {
        int v = (t >= off) ? s[t - off] : 0;
        __syncthreads();
        s[t] += v;
        __syncthreads();
    }
    int run = (t == 0) ? 0 : s[t - 1];
    for (int i = 0; i < 50; i++) {
        cursor[base + i] = run;
        run += counts[base + i];
    }
}

__global__ void k_scatter(const int* __restrict__ recv, int* __restrict__ cursor,
                          int* __restrict__ perm)
{
    int e = blockIdx.x * 256 + threadIdx.x;
    if (e < NE) {
        int r = recv[e];
        int p = atomicAdd(&cursor[r], 1);
        perm[p] = e;
    }
}

// ---------------------------------------------------------------------------
// Node aggregation: one wave per node, gather msg rows via perm, sum, store.
// BF==1: msg is bf16 [E][128]; BF==0: msg is f32 [E][128].
// ---------------------------------------------------------------------------
template<int BF>
__global__ __launch_bounds__(256) void k_nodesum(
    const void* __restrict__ msg, const int* __restrict__ counts,
    const int* __restrict__ cursor_end, const int* __restrict__ perm,
    float* __restrict__ out_nodes)
{
    const int wid = (blockIdx.x * 256 + threadIdx.x) >> 6;   // node id
    const int l = threadIdx.x & 63;
    const int deg = counts[wid];
    const int end = cursor_end[wid];
    const int start = end - deg;
    float a0 = 0.f, a1 = 0.f;
    int en = (deg > 0) ? perm[start] : 0;
    for (int j = 0; j < deg; j++) {
        int e = en;
        if (j + 1 < deg) en = perm[start + j + 1];
        if (BF) {
            unsigned u = *(const unsigned*)((const unsigned short*)msg + (size_t)e * DD + l * 2);
            a0 += __uint_as_float(u << 16);
            a1 += __uint_as_float(u & 0xFFFF0000u);
        } else {
            f32x2 v = *(const f32x2*)((const float*)msg + (size_t)e * DD + l * 2);
            a0 += v[0]; a1 += v[1];
        }
    }
    *(f32x2*)(out_nodes + (size_t)wid * DD + l * 2) = f32x2{a0, a1};
}

// ---------------------------------------------------------------------------
// Main fused edge kernel (two-layer MLP on concat[snd||rcv||edge], MFMA bf16).
// MODE 0: mlp0 -> atomicAdd into out_nodes (legacy fallback)
// MODE 1: mlp given by mlp_base; always store f32 result rows to dstf
// MODE 2: grid.y selects mlp; mlp0 -> bf16 msg rows to dstb, mlp1 -> f32 to out_edges
// ---------------------------------------------------------------------------
template<int MODE>
__global__ __launch_bounds__(256, 3) void k_edge(
    const float* __restrict__ nodes, const float* __restrict__ edges,
    const int* __restrict__ senders, const int* __restrict__ receivers,
    const unsigned short* __restrict__ wt0, const unsigned short* __restrict__ wt1,
    const float* __restrict__ nb0, const float* __restrict__ nb1,
    const float* __restrict__ eb0, const float* __restrict__ eb1,
    float* __restrict__ dstf, unsigned short* __restrict__ dstb,
    float* __restrict__ out_edges, int mlp_base)
{
    __shared__ char lds[52224];
    unsigned short* A1 = (unsigned short*)lds;                 // [128][72] bf16
    unsigned short* B1 = (unsigned short*)(lds + 18432);       // [128][64] bf16 (DMA)
    unsigned short* A2 = (unsigned short*)lds;                 // [128][136] bf16 (aliases A1+B1)
    unsigned short* B2 = (unsigned short*)(lds + 34816);       // [128][64] bf16 (DMA)
    int* ldsSend = (int*)(lds + 51200);
    int* ldsRecv = (int*)(lds + 51712);

    const int t = threadIdx.x;
    const int mlp = (MODE == 1) ? mlp_base : blockIdx.y;
    const size_t e0 = (size_t)blockIdx.x * 128;

    if (t < 128) ldsSend[t] = senders[e0 + t];
    else         ldsRecv[t - 128] = receivers[e0 + t - 128];
    __syncthreads();

    const int rowIdx = t >> 4;
    const int c4 = t & 15;
    int snd[8], rcv[8];
    #pragma unroll
    for (int i = 0; i < 8; i++) {
        snd[i] = ldsSend[i * 16 + rowIdx];
        rcv[i] = ldsRecv[i * 16 + rowIdx];
    }

    const int w = t >> 6, l = t & 63;
    const int l15 = l & 15, q = l >> 4;
    const int wn = (w >> 1) * 64;
    const int wm = (w & 1) * 64;

    const unsigned short* wt0m = wt0 + (size_t)mlp * 49152;
    const unsigned short* wt1m = wt1 + (size_t)mlp * 16384;
    const float* b0 = mlp ? eb0 : nb0;
    const float* b1 = mlp ? eb1 : nb1;

    const f32x4 vzero = {0.f, 0.f, 0.f, 0.f};
    f32x4 acc[4][4];
    #pragma unroll
    for (int i1 = 0; i1 < 4; i1++)
        #pragma unroll
        for (int i2 = 0; i2 < 4; i2++) acc[i1][i2] = vzero;

    // ---------------- layer 1: K = 384, 6 chunks of 64 ----------------
    #pragma unroll
    for (int c = 0; c < 6; c++) {
        #pragma unroll
        for (int i = 0; i < 8; i++) {
            int m = i * 16 + rowIdx;
            const float* p;
            if (c < 2)      p = nodes + (size_t)snd[i] * DD + c * 64 + c4 * 4;
            else if (c < 4) p = nodes + (size_t)rcv[i] * DD + (c - 2) * 64 + c4 * 4;
            else            p = edges + (e0 + m) * DD + (c - 4) * 64 + c4 * 4;
            f32x4 v = *(const f32x4*)p;
            u16x4 h;
            h[0] = f2bf(v[0]); h[1] = f2bf(v[1]); h[2] = f2bf(v[2]); h[3] = f2bf(v[3]);
            *(u16x4*)(A1 + m * 72 + c4 * 4) = h;
        }
        #pragma unroll
        for (int i = 0; i < 4; i++) {
            int idx = i * 256 + w * 64 + l;
            const unsigned short* g = wt0m + (idx >> 3) * 384 + c * 64 + (idx & 7) * 8;
            void* lb = (void*)(lds + 18432 + (i * 256 + w * 64) * 16);
            __builtin_amdgcn_global_load_lds(
                (const __attribute__((address_space(1))) void*)g,
                (__attribute__((address_space(3))) void*)lb, 16, 0, 0);
        }
        __syncthreads();
        #pragma unroll
        for (int kk = 0; kk < 2; kk++) {
            bf16x8 af[4], bfr[4];
            #pragma unroll
            for (int tn = 0; tn < 4; tn++)
                af[tn] = *(const bf16x8*)(B1 + (wn + tn * 16 + l15) * 64 + kk * 32 + q * 8);
            #pragma unroll
            for (int tm = 0; tm < 4; tm++)
                bfr[tm] = *(const bf16x8*)(A1 + (wm + tm * 16 + l15) * 72 + kk * 32 + q * 8);
            #pragma unroll
            for (int tn = 0; tn < 4; tn++)
                #pragma unroll
                for (int tm = 0; tm < 4; tm++)
                    acc[tn][tm] = __builtin_amdgcn_mfma_f32_16x16x32_bf16(
                        af[tn], bfr[tm], acc[tn][tm], 0, 0, 0);
        }
        __syncthreads();
    }

    // ---------------- layer-1 epilogue -> A2[m][n] (bf16) ----------------
    #pragma unroll
    for (int tn = 0; tn < 4; tn++) {
        float bb[4];
        #pragma unroll
        for (int r = 0; r < 4; r++) bb[r] = b0[wn + tn * 16 + q * 4 + r];
        #pragma unroll
        for (int tm = 0; tm < 4; tm++) {
            u16x4 h;
            #pragma unroll
            for (int r = 0; r < 4; r++) {
                float v = lrelu(acc[tn][tm][r] + bb[r]);
                h[r] = f2bf(v);
            }
            int m = wm + tm * 16 + l15;
            *(u16x4*)(A2 + m * 136 + wn + tn * 16 + q * 4) = h;
        }
    }
    #pragma unroll
    for (int i = 0; i < 4; i++) {
        int idx = i * 256 + w * 64 + l;
        const unsigned short* g = wt1m + (idx >> 3) * 128 + (idx & 7) * 8;
        void* lb = (void*)(lds + 34816 + (i * 256 + w * 64) * 16);
        __builtin_amdgcn_global_load_lds(
            (const __attribute__((address_space(1))) void*)g,
            (__attribute__((address_space(3))) void*)lb, 16, 0, 0);
    }
    __syncthreads();

    #pragma unroll
    for (int i1 = 0; i1 < 4; i1++)
        #pragma unroll
        for (int i2 = 0; i2 < 4; i2++) acc[i1][i2] = vzero;

    // ---------------- layer 2: K = 128, 2 chunks of 64 ----------------
    #pragma unroll
    for (int c2 = 0; c2 < 2; c2++) {
        if (c2 == 1) {
            __syncthreads();
            #pragma unroll
            for (int i = 0; i < 4; i++) {
                int idx = i * 256 + w * 64 + l;
                const unsigned short* g = wt1m + (idx >> 3) * 128 + 64 + (idx & 7) * 8;
                void* lb = (void*)(lds + 34816 + (i * 256 + w * 64) * 16);
                __builtin_amdgcn_global_load_lds(
                    (const __attribute__((address_space(1))) void*)g,
                    (__attribute__((address_space(3))) void*)lb, 16, 0, 0);
            }
            __syncthreads();
        }
        #pragma unroll
        for (int kk = 0; kk < 2; kk++) {
            bf16x8 af[4], bfr[4];
            #pragma unroll
            for (int tn = 0; tn < 4; tn++)
                af[tn] = *(const bf16x8*)(B2 + (wn + tn * 16 + l15) * 64 + kk * 32 + q * 8);
            #pragma unroll
            for (int tm = 0; tm < 4; tm++)
                bfr[tm] = *(const bf16x8*)(A2 + (wm + tm * 16 + l15) * 136 + c2 * 64 + kk * 32 + q * 8);
            #pragma unroll
            for (int tn = 0; tn < 4; tn++)
                #pragma unroll
                for (int tm = 0; tm < 4; tm++)
                    acc[tn][tm] = __builtin_amdgcn_mfma_f32_16x16x32_bf16(
                        af[tn], bfr[tm], acc[tn][tm], 0, 0, 0);
        }
    }

    // ---------------- layer-2 epilogue ----------------
    #pragma unroll
    for (int tn = 0; tn < 4; tn++) {
        float bb[4];
        #pragma unroll
        for (int r = 0; r < 4; r++) bb[r] = b1[wn + tn * 16 + q * 4 + r];
        #pragma unroll
        for (int tm = 0; tm < 4; tm++) {
            int m = wm + tm * 16 + l15;
            int n0 = wn + tn * 16 + q * 4;
            f32x4 v;
            #pragma unroll
            for (int r = 0; r < 4; r++) v[r] = lrelu(acc[tn][tm][r] + bb[r]);
            if (MODE == 1) {
                *(f32x4*)(dstf + (e0 + m) * DD + n0) = v;
            } else if (mlp == 1) {
                *(f32x4*)(out_edges + (e0 + m) * DD + n0) = v;
            } else if (MODE == 2) {
                u16x4 h;
                #pragma unroll
                for (int r = 0; r < 4; r++) h[r] = f2bf(v[r]);
                *(u16x4*)(dstb + (e0 + m) * DD + n0) = h;
            } else {
                float* p = dstf + (size_t)ldsRecv[m] * DD + n0;
                #pragma unroll
                for (int r = 0; r < 4; r++) atomicAdd(p + r, v[r]);
            }
        }
    }
}

// ---------------------------------------------------------------------------
// Global-path MLPs in f32 (tiny).
// ---------------------------------------------------------------------------
__global__ void k_globalA(const float* __restrict__ gin, const float* __restrict__ sn,
                          const float* __restrict__ se,
                          const float* __restrict__ W0a, const float* __restrict__ b0a,
                          const float* __restrict__ W1a, const float* __restrict__ b1a,
                          const float* __restrict__ W0b, const float* __restrict__ b0b,
                          const float* __restrict__ W1b, const float* __restrict__ b1b,
                          const float* __restrict__ W0c, const float* __restrict__ b0c,
                          const float* __restrict__ W1c, const float* __restrict__ b1c,
                          float* __restrict__ fargs)
{
    __shared__ float xT[128 * 16];
    __shared__ float hT[128 * 16];
    const int m = blockIdx.y;
    const float* X   = m == 0 ? gin : (m == 1 ? sn : se);
    const float* W0  = m == 0 ? W0a : (m == 1 ? W0b : W0c);
    const float* B0  = m == 0 ? b0a : (m == 1 ? b0b : b0c);
    const float* W1  = m == 0 ? W1a : (m == 1 ? W1b : W1c);
    const float* B1v = m == 0 ? b1a : (m == 1 ? b1b : b1c);
    const int g0 = blockIdx.x * 16, t = threadIdx.x;
    #pragma unroll
    for (int i = 0; i < 8; i++) {
        int idx = i * 256 + t, r = idx >> 7, k = idx & 127;
        xT[k * 16 + r] = X[(size_t)(g0 + r) * DD + k];
    }
    __syncthreads();
    const int n = t & 127, rb = (t >> 7) * 8;
    float a[8] = {};
    for (int k = 0; k < 128; k++) {
        float wv = W0[k * 128 + n];
        #pragma unroll
        for (int j = 0; j < 8; j++) a[j] += xT[k * 16 + rb + j] * wv;
    }
    float bv = B0[n];
    #pragma unroll
    for (int j = 0; j < 8; j++) hT[n * 16 + rb + j] = lrelu(a[j] + bv);
    __syncthreads();
    float a2[8] = {};
    for (int k = 0; k < 128; k++) {
        float wv = W1[k * 128 + n];
        #pragma unroll
        for (int j = 0; j < 8; j++) a2[j] += hT[k * 16 + rb + j] * wv;
    }
    bv = B1v[n];
    #pragma unroll
    for (int j = 0; j < 8; j++)
        fargs[(size_t)(g0 + rb + j) * 384 + m * 128 + n] = lrelu(a2[j] + bv);
}

__global__ void k_globalB(const float* __restrict__ fargs,
                          const float* __restrict__ W0, const float* __restrict__ B0,
                          const float* __restrict__ W1, const float* __restrict__ B1v,
                          float* __restrict__ outg)
{
    __shared__ float xT[384 * 16];
    __shared__ float hT[128 * 16];
    const int g0 = blockIdx.x * 16, t = threadIdx.x;
    for (int r = 0; r < 16; r++)
        for (int k = t; k < 384; k += 256)
            xT[k * 16 + r] = fargs[(size_t)(g0 + r) * 384 + k];
    __syncthreads();
    const int n = t & 127, rb = (t >> 7) * 8;
    float a[8] = {};
    for (int k = 0; k < 384; k++) {
        float wv = W0[k * 128 + n];
        #pragma unroll
        for (int j = 0; j < 8; j++) a[j] += xT[k * 16 + rb + j] * wv;
    }
    float bv = B0[n];
    #pragma unroll
    for (int j = 0; j < 8; j++) hT[n * 16 + rb + j] = lrelu(a[j] + bv);
    __syncthreads();
    float a2[8] = {};
    for (int k = 0; k < 128; k++) {
        float wv = W1[k * 128 + n];
        #pragma unroll
        for (int j = 0; j < 8; j++) a2[j] += hT[k * 16 + rb + j] * wv;
    }
    bv = B1v[n];
    #pragma unroll
    for (int j = 0; j < 8; j++)
        outg[(size_t)(g0 + rb + j) * DD + n] = lrelu(a2[j] + bv);
}

extern "C" void kernel_launch(void* const* d_in, const int* in_sizes, int n_in,
                              void* d_out, int out_size, void* d_ws, size_t ws_size,
                              hipStream_t stream)
{
    const float* nodes     = (const float*)d_in[0];
    const float* edges     = (const float*)d_in[1];
    const float* globals_  = (const float*)d_in[2];
    const int*   senders   = (const int*)d_in[3];
    const int*   receivers = (const int*)d_in[4];
    const int*   n_node    = (const int*)d_in[5];
    const int*   n_edge    = (const int*)d_in[6];
    const float* node_W0 = (const float*)d_in[7];
    const float* node_b0 = (const float*)d_in[8];
    const float* node_W1 = (const float*)d_in[9];
    const float* node_b1 = (const float*)d_in[10];
    const float* edge_W0 = (const float*)d_in[11];
    const float* edge_b0 = (const float*)d_in[12];
    const float* edge_W1 = (const float*)d_in[13];
    const float* edge_b1 = (const float*)d_in[14];
    const float* glob_W0 = (const float*)d_in[15];
    const float* glob_b0 = (const float*)d_in[16];
    const float* glob_W1 = (const float*)d_in[17];
    const float* glob_b1 = (const float*)d_in[18];
    const float* gnode_W0 = (const float*)d_in[19];
    const float* gnode_b0 = (const float*)d_in[20];
    const float* gnode_W1 = (const float*)d_in[21];
    const float* gnode_b1 = (const float*)d_in[22];
    const float* gedge_W0 = (const float*)d_in[23];
    const float* gedge_b0 = (const float*)d_in[24];
    const float* gedge_W1 = (const float*)d_in[25];
    const float* gedge_b1 = (const float*)d_in[26];
    const float* fin_W0 = (const float*)d_in[27];
    const float* fin_b0 = (const float*)d_in[28];
    const float* fin_W1 = (const float*)d_in[29];
    const float* fin_b1 = (const float*)d_in[30];

    float* out_nodes = (float*)d_out;
    float* out_edges = out_nodes + (size_t)NN * DD;
    float* out_glob  = out_edges + (size_t)NE * DD;

    char* ws = (char*)d_ws;
    unsigned short* wt0 = (unsigned short*)ws;              // 196608 B
    unsigned short* wt1 = (unsigned short*)(ws + 196608);   // 65536 B
    float* sn     = (float*)(ws + 262144);                  // 131072 B
    float* se     = (float*)(ws + 393216);                  // 131072 B
    float* fargs  = (float*)(ws + 524288);                  // 393216 B -> 917504
    int*   counts = (int*)(ws + 917504);                    // 204800 B
    int*   cursor = (int*)(ws + 1122304);                   // 204800 B
    int*   perm   = (int*)(ws + 1327104);                   // 1638400 B -> 2965504
    unsigned short* msgb = (unsigned short*)(ws + 2965504); // 104857600 B -> 107823104

    const size_t NEED_FULL = 107823104;
    const size_t NEED_CSR  = 2965504;
    const int mode = (ws_size >= NEED_FULL) ? 2 : (ws_size >= NEED_CSR ? 1 : 0);

    // zero the atomic-accumulated regions
    hipMemsetAsync(sn, 0, 262144, stream);   // sn + se
    if (mode == 0)
        hipMemsetAsync(out_nodes, 0, (size_t)NN * DD * sizeof(float), stream);
    else
        hipMemsetAsync(counts, 0, 204800, stream);

    k_weights<<<512, 256, 0, stream>>>(node_W0, node_W1, edge_W0, edge_W1, wt0, wt1);
    k_segsum<<<dim3(NG, 2), 128, 0, stream>>>(nodes, n_node, sn);
    k_segsum<<<dim3(NG, 16), 128, 0, stream>>>(edges, n_edge, se);

    if (mode != 0) {
        k_hist<<<NE / 256, 256, 0, stream>>>(receivers, counts);
        k_scan<<<1, 1024, 0, stream>>>(counts, cursor);
        k_scatter<<<NE / 256, 256, 0, stream>>>(receivers, cursor, perm);
    }

    if (mode == 2) {
        k_edge<2><<<dim3(NE / 128, 2), 256, 0, stream>>>(nodes, edges, senders, receivers,
            wt0, wt1, node_b0, node_b1, edge_b0, edge_b1,
            (float*)nullptr, msgb, out_edges, 0);
        k_nodesum<1><<<NN / 4, 256, 0, stream>>>(msgb, counts, cursor, perm, out_nodes);
    } else if (mode == 1) {
        // serialized: msg (f32) staged in the out_edges region, then overwritten
        k_edge<1><<<dim3(NE / 128, 1), 256, 0, stream>>>(nodes, edges, senders, receivers,
            wt0, wt1, node_b0, node_b1, edge_b0, edge_b1,
            out_edges, (unsigned short*)nullptr, out_edges, 0);
        k_nodesum<0><<<NN / 4, 256, 0, stream>>>(out_edges, counts, cursor, perm, out_nodes);
        k_edge<1><<<dim3(NE / 128, 1), 256, 0, stream>>>(nodes, edges, senders, receivers,
            wt0, wt1, node_b0, node_b1, edge_b0, edge_b1,
            out_edges, (unsigned short*)nullptr, out_edges, 1);
    } else {
        k_edge<0><<<dim3(NE / 128, 2), 256, 0, stream>>>(nodes, edges, senders, receivers,
            wt0, wt1, node_b0, node_b1, edge_b0, edge_b1,
            out_nodes, (unsigned short*)nullptr, out_edges, 0);
    }

    k_globalA<<<dim3(16, 3), 256, 0, stream>>>(globals_, sn, se,
        glob_W0, glob_b0, glob_W1, glob_b1,
        gnode_W0, gnode_b0, gnode_W1, gnode_b1,
        gedge_W0, gedge_b0, gedge_W1, gedge_b1, fargs);
    k_globalB<<<16, 256, 0, stream>>>(fargs, fin_W0, fin_b0, fin_W1, fin_b1, out_glob);
}